// Round 2
// baseline (997.929 us; speedup 1.0000x reference)
//
#include <hip/hip_runtime.h>

// SSIM loss, round-10: ZERO-LDS register-resident design.
//
// Round-9 post-mortem: FETCH is 1.15x ideal (solved); VALUBusy 47%, occupancy
// ~1.1 waves/SIMD -> latency/occupancy-bound. The 16KB/wave LDS ring caps
// residency, adds ds_write->ds_read critical-path latency every iteration,
// and burns 5.6M bank-conflict cycles. Fix: remove LDS entirely.
//  - Horizontal 11-tap via ds_bpermute cross-lane reads (lane = column).
//    No allocated LDS, no bank conflicts, 10 shuffles x 2 arrays per row.
//    64-lane band -> 54 valid output cols (edge lanes have wrap garbage;
//    garbage is finite real data, den > 0, masked at accumulate).
//  - Vertical 11-tap from a 16-deep REGISTER ring (4 fields x 16 slots).
//    All ring/prefetch indices are compile-time (unroll-16 main loop,
//    strip%16==0) per SROA rules from rounds 2-4.
//  - Prefetch depth 4 rows (slot = row&3, static): 8 dword loads in
//    flight, consumed ~4 rows (~1300 cyc) after issue > ~900 cyc HBM lat.
//  - Grid: 48 img x 10 bands(54 cols) x 8 strips(64 rows) = 3840 blocks
//    x 1 wave. No barriers of any kind. Occupancy is VGPR-bound only.
// Predicted: VALUBusy -> 80-90%, bank conflicts -> 0, dur 112 -> ~45us.
// (Round-11 resubmit: round-10 bench hit GPUAcquisitionTimeout; no data.)

#define WSZ    11
#define RAD    5
#define IMGN   48
#define IMGH   512
#define IMGW   512
#define OUTC   54               // valid output cols per 64-lane band
#define NBAND  10               // ceil(512/54)
#define NSTRIP 8
#define STRIPR 64               // output rows per strip (multiple of 16!)
#define NBLK   (IMGN * NBAND * NSTRIP)   // 3840

// Issue prefetch of input row (ir) into pf slot s. Row clamped (always a
// legal address); OOB rows are zeroed at consume time via fm_. Scalar row
// base (uniform) + per-lane col offset -> global_load_dword v,v,s form.
#define ISSUE(s, ir)                                                    \
    {                                                                   \
        const int rc_ = min(max((ir), 0), IMGH - 1);                    \
        const float* rp_ = p + rc_ * IMGW;                              \
        const float* rq_ = q + rc_ * IMGW;                              \
        pfp[s] = rp_[colc];                                             \
        pft[s] = rq_[colc];                                             \
    }

// Consume pf slot s (input row ir), immediately reissue row ir+4 into the
// same slot (loads stay in flight across ~4 rows of compute), h-blur the
// row via bpermute rotation, deposit 4 fields into ring slot ws.
#define HROW(ws, s, ir)                                                 \
    {                                                                   \
        const float rawp_ = pfp[s], rawt_ = pft[s];                     \
        ISSUE(s, (ir) + 4)                                              \
        const float fm_ =                                               \
            ((unsigned)(ir) < (unsigned)IMGH) ? loadm : 0.f;            \
        const float pv_ = rawp_ * fm_;                                  \
        const float tv_ = rawt_ * fm_;                                  \
        const int pb_ = __float_as_int(pv_);                            \
        const int tb_ = __float_as_int(tv_);                            \
        float f0_ = w[RAD] * pv_;                                       \
        float f1_ = w[RAD] * tv_;                                       \
        float f2_ = w[RAD] * (pv_ * pv_ + tv_ * tv_);                   \
        float f3_ = w[RAD] * (pv_ * tv_);                               \
        _Pragma("unroll")                                               \
        for (int k = 0; k < WSZ; ++k) {                                 \
            if (k == RAD) continue;                                     \
            const float sp_ = __int_as_float(                           \
                __builtin_amdgcn_ds_bpermute(bp[k], pb_));              \
            const float st_ = __int_as_float(                           \
                __builtin_amdgcn_ds_bpermute(bp[k], tb_));              \
            f0_ += w[k] * sp_;                                          \
            f1_ += w[k] * st_;                                          \
            f2_ += w[k] * (sp_ * sp_ + st_ * st_);                      \
            f3_ += w[k] * (sp_ * st_);                                  \
        }                                                               \
        rf0[ws] = f0_; rf1[ws] = f1_; rf2[ws] = f2_; rf3[ws] = f3_;     \
    }

// Vertical 11-tap over ring slots + SSIM for output row m == u (mod 16).
// Window rows m-5..m+5 -> slots (u+11+k)&15; k=10 is the slot HROW just
// wrote, so its FMA lands last in the chain (natural latency overlap).
#define VOUT(u)                                                         \
    {                                                                   \
        float a0_ = 0.f, a1_ = 0.f, a2_ = 0.f, a3_ = 0.f;               \
        _Pragma("unroll")                                               \
        for (int k = 0; k < WSZ; ++k) {                                 \
            const int sk_ = ((u) + 11 + k) & 15;                        \
            a0_ += w[k] * rf0[sk_];                                     \
            a1_ += w[k] * rf1[sk_];                                     \
            a2_ += w[k] * rf2[sk_];                                     \
            a3_ += w[k] * rf3[sk_];                                     \
        }                                                               \
        const float m1_ = a0_, m2_ = a1_;                               \
        const float m1sq_ = m1_ * m1_, m2sq_ = m2_ * m2_;               \
        const float m12_ = m1_ * m2_;                                   \
        const float vs_ = a2_ - m1sq_ - m2sq_;                          \
        const float cv_ = a3_ - m12_;                                   \
        const float num_ = (2.f * m12_ + 1e-4f) * (2.f * cv_ + 9e-4f);  \
        const float den_ =                                              \
            (m1sq_ + m2sq_ + 1e-4f) * (vs_ + 9e-4f) + 1e-8f;            \
        local += outm * (num_ / den_);                                  \
    }

__global__ __launch_bounds__(64, 3) void ssim_vreg_kernel(
    const float* __restrict__ pred,
    const float* __restrict__ target,
    const float* __restrict__ window,
    double* __restrict__ slots)        // NBLK slots, plain write per block
{
    const int t = threadIdx.x;

    // Separable 1D window from row sums; broadcast via shuffles (readlane).
    float rsum = 0.f;
    if (t < WSZ) {
        #pragma unroll
        for (int j = 0; j < WSZ; ++j) rsum += window[t * WSZ + j];
    }
    float w[WSZ];
    #pragma unroll
    for (int k = 0; k < WSZ; ++k) w[k] = __shfl(rsum, k, 64);

    // Block decode: 48 img x 10 bands x 8 strips.
    const int strip = blockIdx.x & (NSTRIP - 1);
    const int rem   = blockIdx.x >> 3;
    const int band  = rem % NBAND;
    const int img   = rem / NBAND;

    // Lane t loads input column band*54 + t - 5 (clamped + masked).
    const int col  = band * OUTC + t - RAD;
    const int colc = min(max(col, 0), IMGW - 1);
    const float loadm = (col >= 0 && col < IMGW) ? 1.f : 0.f;
    // Valid output lanes: 5..58 (full h-neighborhood) and col < 512.
    const float outm =
        (t >= RAD && t < RAD + OUTC && col < IMGW) ? 1.f : 0.f;

    const int base = strip * STRIPR;   // first output row; base % 64 == 0

    const float* __restrict__ p = pred   + (size_t)img * (IMGH * IMGW);
    const float* __restrict__ q = target + (size_t)img * (IMGH * IMGW);

    // bpermute byte addresses for taps (loop-invariant; wrap garbage only
    // reaches invalid output lanes). bp[RAD] unused (center tap in-lane).
    int bp[WSZ];
    #pragma unroll
    for (int k = 0; k < WSZ; ++k) bp[k] = (t + (k - RAD)) << 2;

    float rf0[16], rf1[16], rf2[16], rf3[16];   // register ring, 4 fields
    float pfp[4], pft[4];                       // prefetch ring, depth 4
    float local = 0.f;

    // Initial prefetch: rows base-5..base-2, slot = row & 3 (base%4 == 0).
    ISSUE(3, base - 5)
    ISSUE(0, base - 4)
    ISSUE(1, base - 3)
    ISSUE(2, base - 2)

    // Prologue: h-blur rows base-5..base+4 into ring slots 11..15,0..4.
    #pragma unroll
    for (int j = 0; j < 10; ++j) {
        HROW((j + 11) & 15, (j + 3) & 3, base - 5 + j)
    }

    // Main: 64 output rows, unroll 16 so every ring/pf index is static.
    #pragma unroll 1
    for (int mb = 0; mb < 4; ++mb) {
        const int rb = base + mb * 16;
        #pragma unroll
        for (int u = 0; u < 16; ++u) {
            HROW((u + 5) & 15, (u + 1) & 3, rb + u + 5)
            VOUT(u)
        }
    }

    // Wave shuffle reduce; lane 0 writes this block's slot (no atomic).
    #pragma unroll
    for (int off = 32; off > 0; off >>= 1)
        local += __shfl_down(local, off, 64);
    if (t == 0) slots[blockIdx.x] = (double)local;
}

__global__ __launch_bounds__(256) void ssim_finalize_kernel(
    const double* __restrict__ slots, float* __restrict__ out, double invN)
{
    __shared__ double red[4];
    const int t = threadIdx.x;
    double s = 0.0;
    for (int i = t; i < NBLK; i += 256) s += slots[i];
    #pragma unroll
    for (int off = 32; off > 0; off >>= 1)
        s += __shfl_down(s, off, 64);
    const int lane = t & 63, wid = t >> 6;
    if (lane == 0) red[wid] = s;
    __syncthreads();
    if (t == 0)
        out[0] = (float)(1.0 - (red[0] + red[1] + red[2] + red[3]) * invN);
}

extern "C" void kernel_launch(void* const* d_in, const int* in_sizes, int n_in,
                              void* d_out, int out_size, void* d_ws, size_t ws_size,
                              hipStream_t stream)
{
    const float* pred   = (const float*)d_in[0];
    const float* target = (const float*)d_in[1];
    const float* window = (const float*)d_in[2];
    float*  out   = (float*)d_out;
    double* slots = (double*)d_ws;     // NBLK*8 = 30.7 KB; every slot
                                       // written each launch (poison ok).

    ssim_vreg_kernel<<<NBLK, 64, 0, stream>>>(pred, target, window, slots);

    const double invN = 1.0 / ((double)IMGN * IMGH * IMGW);
    ssim_finalize_kernel<<<1, 256, 0, stream>>>(slots, out, invN);
}

// Round 3
// 983.097 us; speedup vs baseline: 1.0151x; 1.0151x over previous
//
#include <hip/hip_runtime.h>

// SSIM loss, round-12: zero-LDS register-resident design, SPILL-PROOFED.
//
// Round-2 post-mortem: the loop-carried ring arrays rf0..rf3[16]/pfp[4]
// were demoted to scratch (WRITE_SIZE 1.46 GB, VGPR=84, VALUBusy 8%).
// SROA runs before unrolling, and loop-carried mutable arrays can't be
// rescued by store-forwarding across the backedge. Fix: every loop-carried
// value is an individually NAMED scalar (g0_0..g3_15 ring, pfp_0..3/
// pft_0..3 prefetch), with the 16-stage steady state written explicitly.
// Read-only arrays w[]/bp[] keep the round-9-proven pattern.
//  - Horizontal 11-tap via ds_bpermute (lane = column, no LDS alloc).
//  - Vertical 11-tap from the 16-deep named-register ring.
//  - Prefetch depth 4 rows; reissue at consume -> loads in flight ~4 rows.
//  - Grid: 48 img x 10 bands(54 cols) x 8 strips(64 rows) = 3840 blocks
//    x 1 wave, barrier-free.
// Predicted: WRITE_SIZE -> ~0.1 MB, FETCH -> ~150 MB, VALUBusy 70-90%,
// dur 909 -> ~35-50 us.

#define WSZ    11
#define RAD    5
#define IMGN   48
#define IMGH   512
#define IMGW   512
#define OUTC   54               // valid output cols per 64-lane band
#define NBAND  10               // ceil(512/54)
#define NSTRIP 8
#define STRIPR 64               // output rows per strip
#define NBLK   (IMGN * NBAND * NSTRIP)   // 3840

// Issue prefetch of input row (ir) into named pf slot PFS. Row clamped
// (always a legal address); OOB rows are zeroed at consume via fm_.
#define ISSUE(PFS, ir)                                                  \
    {                                                                   \
        const int rc_ = min(max((ir), 0), IMGH - 1);                    \
        pfp_##PFS = p[rc_ * IMGW + colc];                               \
        pft_##PFS = q[rc_ * IMGW + colc];                               \
    }

// Consume pf slot PFS (input row ir), immediately reissue row ir+4 into
// the same slot, h-blur via bpermute, deposit into named ring slot SLOT.
#define HROW(SLOT, PFS, ir)                                             \
    {                                                                   \
        const float rawp_ = pfp_##PFS, rawt_ = pft_##PFS;               \
        ISSUE(PFS, (ir) + 4)                                            \
        const float fm_ =                                               \
            ((unsigned)(ir) < (unsigned)IMGH) ? loadm : 0.f;            \
        const float pv_ = rawp_ * fm_;                                  \
        const float tv_ = rawt_ * fm_;                                  \
        const int pb_ = __float_as_int(pv_);                            \
        const int tb_ = __float_as_int(tv_);                            \
        float f0_ = w[RAD] * pv_;                                       \
        float f1_ = w[RAD] * tv_;                                       \
        float f2_ = w[RAD] * (pv_ * pv_ + tv_ * tv_);                   \
        float f3_ = w[RAD] * (pv_ * tv_);                               \
        _Pragma("unroll")                                               \
        for (int k = 0; k < WSZ; ++k) {                                 \
            if (k == RAD) continue;                                     \
            const float sp_ = __int_as_float(                           \
                __builtin_amdgcn_ds_bpermute(bp[k], pb_));              \
            const float st_ = __int_as_float(                           \
                __builtin_amdgcn_ds_bpermute(bp[k], tb_));              \
            f0_ += w[k] * sp_;                                          \
            f1_ += w[k] * st_;                                          \
            f2_ += w[k] * (sp_ * sp_ + st_ * st_);                      \
            f3_ += w[k] * (sp_ * st_);                                  \
        }                                                               \
        g0_##SLOT = f0_; g1_##SLOT = f1_;                               \
        g2_##SLOT = f2_; g3_##SLOT = f3_;                               \
    }

// Vertical 11-tap over 11 NAMED ring slots (S0..S10 = rows m-5..m+5,
// weights w[0]..w[10]) + SSIM accumulate.
#define VOUT(S0,S1,S2,S3,S4,S5,S6,S7,S8,S9,S10)                         \
    {                                                                   \
        const float a0_ =                                               \
            w[0]*g0_##S0 + w[1]*g0_##S1 + w[2]*g0_##S2 + w[3]*g0_##S3   \
          + w[4]*g0_##S4 + w[5]*g0_##S5 + w[6]*g0_##S6 + w[7]*g0_##S7   \
          + w[8]*g0_##S8 + w[9]*g0_##S9 + w[10]*g0_##S10;               \
        const float a1_ =                                               \
            w[0]*g1_##S0 + w[1]*g1_##S1 + w[2]*g1_##S2 + w[3]*g1_##S3   \
          + w[4]*g1_##S4 + w[5]*g1_##S5 + w[6]*g1_##S6 + w[7]*g1_##S7   \
          + w[8]*g1_##S8 + w[9]*g1_##S9 + w[10]*g1_##S10;               \
        const float a2_ =                                               \
            w[0]*g2_##S0 + w[1]*g2_##S1 + w[2]*g2_##S2 + w[3]*g2_##S3   \
          + w[4]*g2_##S4 + w[5]*g2_##S5 + w[6]*g2_##S6 + w[7]*g2_##S7   \
          + w[8]*g2_##S8 + w[9]*g2_##S9 + w[10]*g2_##S10;               \
        const float a3_ =                                               \
            w[0]*g3_##S0 + w[1]*g3_##S1 + w[2]*g3_##S2 + w[3]*g3_##S3   \
          + w[4]*g3_##S4 + w[5]*g3_##S5 + w[6]*g3_##S6 + w[7]*g3_##S7   \
          + w[8]*g3_##S8 + w[9]*g3_##S9 + w[10]*g3_##S10;               \
        const float m1_ = a0_, m2_ = a1_;                               \
        const float m1sq_ = m1_ * m1_, m2sq_ = m2_ * m2_;               \
        const float m12_ = m1_ * m2_;                                   \
        const float vs_ = a2_ - m1sq_ - m2sq_;                          \
        const float cv_ = a3_ - m12_;                                   \
        const float num_ = (2.f * m12_ + 1e-4f) * (2.f * cv_ + 9e-4f);  \
        const float den_ =                                              \
            (m1sq_ + m2sq_ + 1e-4f) * (vs_ + 9e-4f) + 1e-8f;            \
        local += outm * (num_ / den_);                                  \
    }

__global__ __launch_bounds__(64, 3) void ssim_vreg_kernel(
    const float* __restrict__ pred,
    const float* __restrict__ target,
    const float* __restrict__ window,
    double* __restrict__ slots)        // NBLK slots, plain write per block
{
    const int t = threadIdx.x;

    // Separable 1D window from row sums; broadcast via shuffles.
    float rsum = 0.f;
    if (t < WSZ) {
        #pragma unroll
        for (int j = 0; j < WSZ; ++j) rsum += window[t * WSZ + j];
    }
    float w[WSZ];
    #pragma unroll
    for (int k = 0; k < WSZ; ++k) w[k] = __shfl(rsum, k, 64);

    // Block decode: 48 img x 10 bands x 8 strips.
    const int strip = blockIdx.x & (NSTRIP - 1);
    const int rem   = blockIdx.x >> 3;
    const int band  = rem % NBAND;
    const int img   = rem / NBAND;

    // Lane t covers input column band*54 + t - 5 (clamped + masked).
    const int col  = band * OUTC + t - RAD;
    const int colc = min(max(col, 0), IMGW - 1);
    const float loadm = (col >= 0 && col < IMGW) ? 1.f : 0.f;
    // Valid output lanes: 5..58 (full h-neighborhood) and col < 512.
    const float outm =
        (t >= RAD && t < RAD + OUTC && col < IMGW) ? 1.f : 0.f;

    const int base = strip * STRIPR;   // first output row; base % 16 == 0

    const float* __restrict__ p = pred   + (size_t)img * (IMGH * IMGW);
    const float* __restrict__ q = target + (size_t)img * (IMGH * IMGW);

    // bpermute byte addresses (loop-invariant, read-only array: OK).
    int bp[WSZ];
    #pragma unroll
    for (int k = 0; k < WSZ; ++k) bp[k] = (t + (k - RAD)) << 2;

    // NAMED register ring: slot i holds row r (r mod 16 == i), 4 fields.
    float g0_0=0,g0_1=0,g0_2=0,g0_3=0,g0_4=0,g0_5=0,g0_6=0,g0_7=0,
          g0_8=0,g0_9=0,g0_10=0,g0_11=0,g0_12=0,g0_13=0,g0_14=0,g0_15=0;
    float g1_0=0,g1_1=0,g1_2=0,g1_3=0,g1_4=0,g1_5=0,g1_6=0,g1_7=0,
          g1_8=0,g1_9=0,g1_10=0,g1_11=0,g1_12=0,g1_13=0,g1_14=0,g1_15=0;
    float g2_0=0,g2_1=0,g2_2=0,g2_3=0,g2_4=0,g2_5=0,g2_6=0,g2_7=0,
          g2_8=0,g2_9=0,g2_10=0,g2_11=0,g2_12=0,g2_13=0,g2_14=0,g2_15=0;
    float g3_0=0,g3_1=0,g3_2=0,g3_3=0,g3_4=0,g3_5=0,g3_6=0,g3_7=0,
          g3_8=0,g3_9=0,g3_10=0,g3_11=0,g3_12=0,g3_13=0,g3_14=0,g3_15=0;
    // Named prefetch ring, depth 4 (slot = row & 3).
    float pfp_0, pfp_1, pfp_2, pfp_3, pft_0, pft_1, pft_2, pft_3;
    float local = 0.f;

    // Initial prefetch: rows base-5..base-2 into slot row&3 (base%4==0).
    ISSUE(3, base - 5)
    ISSUE(0, base - 4)
    ISSUE(1, base - 3)
    ISSUE(2, base - 2)

    // Prologue: h-blur rows base-5..base+4 into ring slots row&15.
    HROW(11, 3, base - 5)
    HROW(12, 0, base - 4)
    HROW(13, 1, base - 3)
    HROW(14, 2, base - 2)
    HROW(15, 3, base - 1)
    HROW(0,  0, base + 0)
    HROW(1,  1, base + 1)
    HROW(2,  2, base + 2)
    HROW(3,  3, base + 3)
    HROW(4,  0, base + 4)

    // Main: 4 x 16 output rows; every ring/pf reference is a named scalar.
    #pragma unroll 1
    for (int mb = 0; mb < 4; ++mb) {
        const int rb = base + mb * 16;
        HROW(5,  1, rb + 5)   VOUT(11,12,13,14,15,0,1,2,3,4,5)
        HROW(6,  2, rb + 6)   VOUT(12,13,14,15,0,1,2,3,4,5,6)
        HROW(7,  3, rb + 7)   VOUT(13,14,15,0,1,2,3,4,5,6,7)
        HROW(8,  0, rb + 8)   VOUT(14,15,0,1,2,3,4,5,6,7,8)
        HROW(9,  1, rb + 9)   VOUT(15,0,1,2,3,4,5,6,7,8,9)
        HROW(10, 2, rb + 10)  VOUT(0,1,2,3,4,5,6,7,8,9,10)
        HROW(11, 3, rb + 11)  VOUT(1,2,3,4,5,6,7,8,9,10,11)
        HROW(12, 0, rb + 12)  VOUT(2,3,4,5,6,7,8,9,10,11,12)
        HROW(13, 1, rb + 13)  VOUT(3,4,5,6,7,8,9,10,11,12,13)
        HROW(14, 2, rb + 14)  VOUT(4,5,6,7,8,9,10,11,12,13,14)
        HROW(15, 3, rb + 15)  VOUT(5,6,7,8,9,10,11,12,13,14,15)
        HROW(0,  0, rb + 16)  VOUT(6,7,8,9,10,11,12,13,14,15,0)
        HROW(1,  1, rb + 17)  VOUT(7,8,9,10,11,12,13,14,15,0,1)
        HROW(2,  2, rb + 18)  VOUT(8,9,10,11,12,13,14,15,0,1,2)
        HROW(3,  3, rb + 19)  VOUT(9,10,11,12,13,14,15,0,1,2,3)
        HROW(4,  0, rb + 20)  VOUT(10,11,12,13,14,15,0,1,2,3,4)
    }

    // Wave shuffle reduce; lane 0 writes this block's slot (no atomic).
    #pragma unroll
    for (int off = 32; off > 0; off >>= 1)
        local += __shfl_down(local, off, 64);
    if (t == 0) slots[blockIdx.x] = (double)local;
}

__global__ __launch_bounds__(256) void ssim_finalize_kernel(
    const double* __restrict__ slots, float* __restrict__ out, double invN)
{
    __shared__ double red[4];
    const int t = threadIdx.x;
    double s = 0.0;
    for (int i = t; i < NBLK; i += 256) s += slots[i];
    #pragma unroll
    for (int off = 32; off > 0; off >>= 1)
        s += __shfl_down(s, off, 64);
    const int lane = t & 63, wid = t >> 6;
    if (lane == 0) red[wid] = s;
    __syncthreads();
    if (t == 0)
        out[0] = (float)(1.0 - (red[0] + red[1] + red[2] + red[3]) * invN);
}

extern "C" void kernel_launch(void* const* d_in, const int* in_sizes, int n_in,
                              void* d_out, int out_size, void* d_ws, size_t ws_size,
                              hipStream_t stream)
{
    const float* pred   = (const float*)d_in[0];
    const float* target = (const float*)d_in[1];
    const float* window = (const float*)d_in[2];
    float*  out   = (float*)d_out;
    double* slots = (double*)d_ws;     // NBLK*8 = 30.7 KB; every slot
                                       // written each launch (poison ok).

    ssim_vreg_kernel<<<NBLK, 64, 0, stream>>>(pred, target, window, slots);

    const double invN = 1.0 / ((double)IMGN * IMGH * IMGW);
    ssim_finalize_kernel<<<1, 256, 0, stream>>>(slots, out, invN);
}

// Round 4
// 274.620 us; speedup vs baseline: 3.6339x; 3.5798x over previous
//
#include <hip/hip_runtime.h>

// SSIM loss, round-13: zero-LDS register design, REGISTER-BUDGET FIXED.
//
// Round-3 post-mortem: named scalars STILL spilled (WRITE_SIZE 1.32 GB of
// scratch stores, VGPR=84 — identical to round 2's array version). Named
// locals are SSA; they only reach memory via register-allocator spilling.
// VGPR=84 with __launch_bounds__(64,3) says the waves-per-EU request
// capped the allocator near 512/6 regs — half what the documented
// semantics imply — and the ~130-reg working set (64 ring + 8 pf + 11 w
// + 11 bp + addressing) cannot fit. Fix:
//  1. __launch_bounds__(64, 1): budget >= 256 regs under ANY
//     interpretation; the working set fits with margin -> zero spill.
//  2. bp[11] address array -> single base (t-RAD)<<2 + constant offsets
//     0..40 folded into ds_bpermute offset immediates (-10 regs).
// Everything else unchanged from round 12 (algorithm verified: passed).
// Predicted: WRITE_SIZE 1.32 GB -> ~0.1 MB, FETCH -> ~150 MB, VGPR ->
// 130-180, VALUBusy -> 60-90%, dur 946 -> ~35-60 us.

#define WSZ    11
#define RAD    5
#define IMGN   48
#define IMGH   512
#define IMGW   512
#define OUTC   54               // valid output cols per 64-lane band
#define NBAND  10               // ceil(512/54)
#define NSTRIP 8
#define STRIPR 64               // output rows per strip
#define NBLK   (IMGN * NBAND * NSTRIP)   // 3840

// Issue prefetch of input row (ir) into named pf slot PFS. Row clamped
// (always a legal address); OOB rows are zeroed at consume via fm_.
#define ISSUE(PFS, ir)                                                  \
    {                                                                   \
        const int rc_ = min(max((ir), 0), IMGH - 1);                    \
        pfp_##PFS = p[rc_ * IMGW + colc];                               \
        pft_##PFS = q[rc_ * IMGW + colc];                               \
    }

// Consume pf slot PFS (input row ir), immediately reissue row ir+4 into
// the same slot, h-blur via bpermute, deposit into named ring slot SLOT.
// Tap k reads lane (t-5+k): address = bpbase + 4k, 4k in [0,40] folds
// into the DS offset immediate. Wrap garbage reaches only masked lanes.
#define HROW(SLOT, PFS, ir)                                             \
    {                                                                   \
        const float rawp_ = pfp_##PFS, rawt_ = pft_##PFS;               \
        ISSUE(PFS, (ir) + 4)                                            \
        const float fm_ =                                               \
            ((unsigned)(ir) < (unsigned)IMGH) ? loadm : 0.f;            \
        const float pv_ = rawp_ * fm_;                                  \
        const float tv_ = rawt_ * fm_;                                  \
        const int pb_ = __float_as_int(pv_);                            \
        const int tb_ = __float_as_int(tv_);                            \
        float f0_ = w[RAD] * pv_;                                       \
        float f1_ = w[RAD] * tv_;                                       \
        float f2_ = w[RAD] * (pv_ * pv_ + tv_ * tv_);                   \
        float f3_ = w[RAD] * (pv_ * tv_);                               \
        _Pragma("unroll")                                               \
        for (int k = 0; k < WSZ; ++k) {                                 \
            if (k == RAD) continue;                                     \
            const float sp_ = __int_as_float(                           \
                __builtin_amdgcn_ds_bpermute(bpbase + (k << 2), pb_));  \
            const float st_ = __int_as_float(                           \
                __builtin_amdgcn_ds_bpermute(bpbase + (k << 2), tb_));  \
            f0_ += w[k] * sp_;                                          \
            f1_ += w[k] * st_;                                          \
            f2_ += w[k] * (sp_ * sp_ + st_ * st_);                      \
            f3_ += w[k] * (sp_ * st_);                                  \
        }                                                               \
        g0_##SLOT = f0_; g1_##SLOT = f1_;                               \
        g2_##SLOT = f2_; g3_##SLOT = f3_;                               \
    }

// Vertical 11-tap over 11 NAMED ring slots (S0..S10 = rows m-5..m+5,
// weights w[0]..w[10]) + SSIM accumulate.
#define VOUT(S0,S1,S2,S3,S4,S5,S6,S7,S8,S9,S10)                         \
    {                                                                   \
        const float a0_ =                                               \
            w[0]*g0_##S0 + w[1]*g0_##S1 + w[2]*g0_##S2 + w[3]*g0_##S3   \
          + w[4]*g0_##S4 + w[5]*g0_##S5 + w[6]*g0_##S6 + w[7]*g0_##S7   \
          + w[8]*g0_##S8 + w[9]*g0_##S9 + w[10]*g0_##S10;               \
        const float a1_ =                                               \
            w[0]*g1_##S0 + w[1]*g1_##S1 + w[2]*g1_##S2 + w[3]*g1_##S3   \
          + w[4]*g1_##S4 + w[5]*g1_##S5 + w[6]*g1_##S6 + w[7]*g1_##S7   \
          + w[8]*g1_##S8 + w[9]*g1_##S9 + w[10]*g1_##S10;               \
        const float a2_ =                                               \
            w[0]*g2_##S0 + w[1]*g2_##S1 + w[2]*g2_##S2 + w[3]*g2_##S3   \
          + w[4]*g2_##S4 + w[5]*g2_##S5 + w[6]*g2_##S6 + w[7]*g2_##S7   \
          + w[8]*g2_##S8 + w[9]*g2_##S9 + w[10]*g2_##S10;               \
        const float a3_ =                                               \
            w[0]*g3_##S0 + w[1]*g3_##S1 + w[2]*g3_##S2 + w[3]*g3_##S3   \
          + w[4]*g3_##S4 + w[5]*g3_##S5 + w[6]*g3_##S6 + w[7]*g3_##S7   \
          + w[8]*g3_##S8 + w[9]*g3_##S9 + w[10]*g3_##S10;               \
        const float m1_ = a0_, m2_ = a1_;                               \
        const float m1sq_ = m1_ * m1_, m2sq_ = m2_ * m2_;               \
        const float m12_ = m1_ * m2_;                                   \
        const float vs_ = a2_ - m1sq_ - m2sq_;                          \
        const float cv_ = a3_ - m12_;                                   \
        const float num_ = (2.f * m12_ + 1e-4f) * (2.f * cv_ + 9e-4f);  \
        const float den_ =                                              \
            (m1sq_ + m2sq_ + 1e-4f) * (vs_ + 9e-4f) + 1e-8f;            \
        local += outm * (num_ / den_);                                  \
    }

__global__ __launch_bounds__(64, 1) void ssim_vreg_kernel(
    const float* __restrict__ pred,
    const float* __restrict__ target,
    const float* __restrict__ window,
    double* __restrict__ slots)        // NBLK slots, plain write per block
{
    const int t = threadIdx.x;

    // Separable 1D window from row sums; broadcast via shuffles.
    float rsum = 0.f;
    if (t < WSZ) {
        #pragma unroll
        for (int j = 0; j < WSZ; ++j) rsum += window[t * WSZ + j];
    }
    float w[WSZ];
    #pragma unroll
    for (int k = 0; k < WSZ; ++k) w[k] = __shfl(rsum, k, 64);

    // Block decode: 48 img x 10 bands x 8 strips.
    const int strip = blockIdx.x & (NSTRIP - 1);
    const int rem   = blockIdx.x >> 3;
    const int band  = rem % NBAND;
    const int img   = rem / NBAND;

    // Lane t covers input column band*54 + t - 5 (clamped + masked).
    const int col  = band * OUTC + t - RAD;
    const int colc = min(max(col, 0), IMGW - 1);
    const float loadm = (col >= 0 && col < IMGW) ? 1.f : 0.f;
    // Valid output lanes: 5..58 (full h-neighborhood) and col < 512.
    const float outm =
        (t >= RAD && t < RAD + OUTC && col < IMGW) ? 1.f : 0.f;

    const int base = strip * STRIPR;   // first output row; base % 16 == 0

    const float* __restrict__ p = pred   + (size_t)img * (IMGH * IMGW);
    const float* __restrict__ q = target + (size_t)img * (IMGH * IMGW);

    // Single bpermute base: tap k of lane t pulls lane (t-5+k), i.e.
    // byte addr ((t-5)<<2) + (k<<2); k<<2 folds into the DS immediate.
    const int bpbase = (t - RAD) << 2;

    // NAMED register ring: slot i holds row r (r mod 16 == i), 4 fields.
    float g0_0=0,g0_1=0,g0_2=0,g0_3=0,g0_4=0,g0_5=0,g0_6=0,g0_7=0,
          g0_8=0,g0_9=0,g0_10=0,g0_11=0,g0_12=0,g0_13=0,g0_14=0,g0_15=0;
    float g1_0=0,g1_1=0,g1_2=0,g1_3=0,g1_4=0,g1_5=0,g1_6=0,g1_7=0,
          g1_8=0,g1_9=0,g1_10=0,g1_11=0,g1_12=0,g1_13=0,g1_14=0,g1_15=0;
    float g2_0=0,g2_1=0,g2_2=0,g2_3=0,g2_4=0,g2_5=0,g2_6=0,g2_7=0,
          g2_8=0,g2_9=0,g2_10=0,g2_11=0,g2_12=0,g2_13=0,g2_14=0,g2_15=0;
    float g3_0=0,g3_1=0,g3_2=0,g3_3=0,g3_4=0,g3_5=0,g3_6=0,g3_7=0,
          g3_8=0,g3_9=0,g3_10=0,g3_11=0,g3_12=0,g3_13=0,g3_14=0,g3_15=0;
    // Named prefetch ring, depth 4 (slot = row & 3).
    float pfp_0, pfp_1, pfp_2, pfp_3, pft_0, pft_1, pft_2, pft_3;
    float local = 0.f;

    // Initial prefetch: rows base-5..base-2 into slot row&3 (base%4==0).
    ISSUE(3, base - 5)
    ISSUE(0, base - 4)
    ISSUE(1, base - 3)
    ISSUE(2, base - 2)

    // Prologue: h-blur rows base-5..base+4 into ring slots row&15.
    HROW(11, 3, base - 5)
    HROW(12, 0, base - 4)
    HROW(13, 1, base - 3)
    HROW(14, 2, base - 2)
    HROW(15, 3, base - 1)
    HROW(0,  0, base + 0)
    HROW(1,  1, base + 1)
    HROW(2,  2, base + 2)
    HROW(3,  3, base + 3)
    HROW(4,  0, base + 4)

    // Main: 4 x 16 output rows; every ring/pf reference is a named scalar.
    #pragma unroll 1
    for (int mb = 0; mb < 4; ++mb) {
        const int rb = base + mb * 16;
        HROW(5,  1, rb + 5)   VOUT(11,12,13,14,15,0,1,2,3,4,5)
        HROW(6,  2, rb + 6)   VOUT(12,13,14,15,0,1,2,3,4,5,6)
        HROW(7,  3, rb + 7)   VOUT(13,14,15,0,1,2,3,4,5,6,7)
        HROW(8,  0, rb + 8)   VOUT(14,15,0,1,2,3,4,5,6,7,8)
        HROW(9,  1, rb + 9)   VOUT(15,0,1,2,3,4,5,6,7,8,9)
        HROW(10, 2, rb + 10)  VOUT(0,1,2,3,4,5,6,7,8,9,10)
        HROW(11, 3, rb + 11)  VOUT(1,2,3,4,5,6,7,8,9,10,11)
        HROW(12, 0, rb + 12)  VOUT(2,3,4,5,6,7,8,9,10,11,12)
        HROW(13, 1, rb + 13)  VOUT(3,4,5,6,7,8,9,10,11,12,13)
        HROW(14, 2, rb + 14)  VOUT(4,5,6,7,8,9,10,11,12,13,14)
        HROW(15, 3, rb + 15)  VOUT(5,6,7,8,9,10,11,12,13,14,15)
        HROW(0,  0, rb + 16)  VOUT(6,7,8,9,10,11,12,13,14,15,0)
        HROW(1,  1, rb + 17)  VOUT(7,8,9,10,11,12,13,14,15,0,1)
        HROW(2,  2, rb + 18)  VOUT(8,9,10,11,12,13,14,15,0,1,2)
        HROW(3,  3, rb + 19)  VOUT(9,10,11,12,13,14,15,0,1,2,3)
        HROW(4,  0, rb + 20)  VOUT(10,11,12,13,14,15,0,1,2,3,4)
    }

    // Wave shuffle reduce; lane 0 writes this block's slot (no atomic).
    #pragma unroll
    for (int off = 32; off > 0; off >>= 1)
        local += __shfl_down(local, off, 64);
    if (t == 0) slots[blockIdx.x] = (double)local;
}

__global__ __launch_bounds__(256) void ssim_finalize_kernel(
    const double* __restrict__ slots, float* __restrict__ out, double invN)
{
    __shared__ double red[4];
    const int t = threadIdx.x;
    double s = 0.0;
    for (int i = t; i < NBLK; i += 256) s += slots[i];
    #pragma unroll
    for (int off = 32; off > 0; off >>= 1)
        s += __shfl_down(s, off, 64);
    const int lane = t & 63, wid = t >> 6;
    if (lane == 0) red[wid] = s;
    __syncthreads();
    if (t == 0)
        out[0] = (float)(1.0 - (red[0] + red[1] + red[2] + red[3]) * invN);
}

extern "C" void kernel_launch(void* const* d_in, const int* in_sizes, int n_in,
                              void* d_out, int out_size, void* d_ws, size_t ws_size,
                              hipStream_t stream)
{
    const float* pred   = (const float*)d_in[0];
    const float* target = (const float*)d_in[1];
    const float* window = (const float*)d_in[2];
    float*  out   = (float*)d_out;
    double* slots = (double*)d_ws;     // NBLK*8 = 30.7 KB; every slot
                                       // written each launch (poison ok).

    ssim_vreg_kernel<<<NBLK, 64, 0, stream>>>(pred, target, window, slots);

    const double invN = 1.0 / ((double)IMGN * IMGH * IMGW);
    ssim_finalize_kernel<<<1, 256, 0, stream>>>(slots, out, invN);
}